// Round 11
// baseline (227.835 us; speedup 1.0000x reference)
//
#include <hip/hip_runtime.h>

// Flash attention forward, fp32 in/out, fp16 MFMA compute.
// B=8, SQ=SK=4096, D=64. scores = (Q/x5) K^T ; softmax ; O = P V.
// R28 = R16 partial body (61.0us best; R26's TK=128 reverted: 63.1) + combine
// FUSED into the partial epilogue (split-K last-block-combines):
//  - every block stores Ap/ML, __threadfence() (device scope, cross-XCD),
//    atomicAdd ticket per (b,qi); 4th arrival acquires + combines 256 rows
//    and writes O directly. Tickets zeroed by prepass (runs first in-stream).
//  - combine kernel DELETED: 3 launches -> 2; saves combine duration + gap.
// Rationale: total-vs-partial gap is ~72us across ALL configs (R12/15/19/22/
// 26) -- the non-partial fixed cost is now the biggest target; partial is at
// a schedule plateau (R20/R24/R26 all <=0; occupancy dead R11/R14/R22).
// Kept: 32x32x16 swapped QK^T, in-register mt-interleaved softmax, permlane
// P redistribution, fused-l ones-MFMA, kf/vf once per kt, setprio clusters,
// defer-max THR=11.5, normalized Ap, dbuf global_load_lds BK=64 staging,
// XCD-affine grid, KSPLIT=4, launch_bounds(256,2).

typedef _Float16 f16x8 __attribute__((ext_vector_type(8)));
typedef _Float16 f16x4 __attribute__((ext_vector_type(4)));
typedef __fp16   h16x2 __attribute__((ext_vector_type(2)));
typedef float    f32x4 __attribute__((ext_vector_type(4)));
typedef float    f32x16 __attribute__((ext_vector_type(16)));

constexpr int kB  = 8;
constexpr int kSQ = 4096;
constexpr int kSK = 4096;
constexpr int kD  = 64;
constexpr int KSPLIT = 4;
constexpr int SKH = kSK / KSPLIT;     // 1024 keys per split
constexpr int BQ  = 256;              // 4 waves x 2 M-tiles x 32 Q rows
constexpr int MT  = 2;
constexpr int BK  = 64;
constexpr int NQI = kSQ / BQ;         // 16 q-blocks per batch
constexpr size_t APART = (size_t)kB * kSQ * kD;
constexpr float kLog2e = 1.44269504088896340736f;
constexpr float kDeferThr = 11.5f;    // exp2-domain (~8 nats); P <= 2^11.5

static __device__ __forceinline__ f16x4 pack4(float a, float b, float c, float d) {
    h16x2 p0 = __builtin_amdgcn_cvt_pkrtz(a, b);
    h16x2 p1 = __builtin_amdgcn_cvt_pkrtz(c, d);
    f16x4 r;
    r[0] = (_Float16)p0[0]; r[1] = (_Float16)p0[1];
    r[2] = (_Float16)p1[0]; r[3] = (_Float16)p1[1];
    return r;
}
static __device__ __forceinline__ f16x8 pack8(const float4& a, const float4& c) {
    f16x4 lo = pack4(a.x, a.y, a.z, a.w);
    f16x4 hi = pack4(c.x, c.y, c.z, c.w);
    f16x8 f;
    f[0] = lo[0]; f[1] = lo[1]; f[2] = lo[2]; f[3] = lo[3];
    f[4] = hi[0]; f[5] = hi[1]; f[6] = hi[2]; f[7] = hi[3];
    return f;
}
static __device__ __forceinline__ unsigned pkrtz_u(float a, float b) {
    union { h16x2 h; unsigned u; } cv;
    cv.h = __builtin_amdgcn_cvt_pkrtz(a, b);
    return cv.u;
}
static __device__ __forceinline__ float xhalf_max(float x) {
    // max(x[lane], x[lane^32]) in every lane, VALU-only.
    union { float f; unsigned u; } uv; uv.f = x;
    auto pr = __builtin_amdgcn_permlane32_swap(uv.u, uv.u, false, false);
    union { unsigned u; float f; } r0, r1;
    r0.u = pr[0]; r1.u = pr[1];
    return fmaxf(r0.f, r1.f);
}

typedef const __attribute__((address_space(1))) unsigned int* gu32p;
typedef __attribute__((address_space(3))) unsigned int* lu32p;
static __device__ __forceinline__ void gload_lds16(const void* g, void* l) {
    __builtin_amdgcn_global_load_lds((gu32p)g, (lu32p)l, 16, 0, 0);
}

// P slice (8 regs of one 32-key C-block) -> f16x8 PV fragment.
// C/D rows: key = (r&3)+8*(r>>2)+4*hi. Pair cvtpk(p[2i],p[2i+1]) with
// cvtpk(p[2i+4],p[2i+5]); one permlane32_swap fills two output words.
#define PA_SLICE(dst, sv, rb) do {                                          \
    unsigned c0 = pkrtz_u((sv)[(rb)+0], (sv)[(rb)+1]);                      \
    unsigned c1 = pkrtz_u((sv)[(rb)+2], (sv)[(rb)+3]);                      \
    unsigned c2 = pkrtz_u((sv)[(rb)+4], (sv)[(rb)+5]);                      \
    unsigned c3 = pkrtz_u((sv)[(rb)+6], (sv)[(rb)+7]);                      \
    auto r02 = __builtin_amdgcn_permlane32_swap(c0, c2, false, false);      \
    auto r13 = __builtin_amdgcn_permlane32_swap(c1, c3, false, false);      \
    union { unsigned u[4]; f16x8 v; } _r;                                   \
    _r.u[0] = r02[0]; _r.u[1] = r13[0]; _r.u[2] = r02[1]; _r.u[3] = r13[1]; \
    dst = _r.v;                                                             \
} while (0)

// ---------------- pre-pass: K -> Kh (swizzled fp16), V -> Vt (transposed,
// tiled, swizzled fp16). Also zeroes the split-K tickets (runs before
// partial in-stream). Kh[b][k][blk fb^(k&7)][8]; Vt[b][kt][f][blk kb^(f&7)][8].
__global__ __launch_bounds__(256, 2)
void fattn_prepass(const float* __restrict__ Kg,
                   const float* __restrict__ Vg,
                   _Float16* __restrict__ Kh,
                   _Float16* __restrict__ Vt,
                   int* __restrict__ cnt)
{
    __shared__ _Float16 tr[kD][BK];

    const int tid = threadIdx.x;
    const int kt  = blockIdx.x;
    const int b   = blockIdx.y;

    if (kt == 0 && tid < NQI) cnt[b * NQI + tid] = 0;   // zero tickets

    const int k = tid >> 2;
    const int p = tid & 3;
    const int gk = kt * BK + k;

    {
        const float* src = Kg + ((size_t)b * kSK + gk) * kD + p * 16;
        const float4 a0 = *(const float4*)(src + 0);
        const float4 a1 = *(const float4*)(src + 4);
        const float4 a2 = *(const float4*)(src + 8);
        const float4 a3 = *(const float4*)(src + 12);
        _Float16* dst = Kh + ((size_t)b * kSK + gk) * kD;
        const int fb0 = 2 * p, fb1 = 2 * p + 1;
        *(f16x8*)&dst[(fb0 ^ (gk & 7)) * 8] = pack8(a0, a1);
        *(f16x8*)&dst[(fb1 ^ (gk & 7)) * 8] = pack8(a2, a3);
    }
    {
        const float* src = Vg + ((size_t)b * kSK + gk) * kD + p * 16;
        const float4 a0 = *(const float4*)(src + 0);
        const float4 a1 = *(const float4*)(src + 4);
        const float4 a2 = *(const float4*)(src + 8);
        const float4 a3 = *(const float4*)(src + 12);
        const float v[16] = {a0.x,a0.y,a0.z,a0.w, a1.x,a1.y,a1.z,a1.w,
                             a2.x,a2.y,a2.z,a2.w, a3.x,a3.y,a3.z,a3.w};
#pragma unroll
        for (int j = 0; j < 16; ++j)
            tr[p * 16 + j][k] = (_Float16)v[j];
    }
    __syncthreads();
    {
        const int f  = tid >> 2;
        const int p2 = tid & 3;
        const f16x8 b0 = *(const f16x8*)&tr[f][p2 * 16 + 0];
        const f16x8 b1 = *(const f16x8*)&tr[f][p2 * 16 + 8];
        _Float16* dst = Vt + (((size_t)b * 64 + kt) * kD + f) * BK;
        const int kb0 = 2 * p2, kb1 = 2 * p2 + 1;
        *(f16x8*)&dst[(kb0 ^ (f & 7)) * 8] = b0;
        *(f16x8*)&dst[(kb1 ^ (f & 7)) * 8] = b1;
    }
}

// ---------------- main partial kernel (32x32x16 MFMA, MT=2) + fused combine ----------------
__global__ __launch_bounds__(256, 2)
void fattn_partial(const float* __restrict__ Qg,
                   const _Float16* __restrict__ Kh,
                   const _Float16* __restrict__ Vt,
                   const float* __restrict__ sdiv,
                   _Float16* __restrict__ Ap,   // [KSPLIT][B][SQ][D] NORMALIZED (O/l)
                   float2* __restrict__ MLp,    // [KSPLIT][B][SQ] (m,l) exp2-domain
                   int* __restrict__ cnt,       // [B][NQI] split-K tickets
                   float* __restrict__ Og)      // [B][SQ][D] final output
{
    __shared__ __align__(16) _Float16 sK[2][BK * kD];   // 16 KB
    __shared__ __align__(16) _Float16 sV[2][kD * BK];   // 16 KB
    __shared__ int sTicket;

    const int tid  = threadIdx.x;
    const int w    = tid >> 6;
    const int lane = tid & 63;
    const int l31  = lane & 31;
    const int hi   = lane >> 5;

    // XCD-affine decode: flat = c + 32*q; c = (b,ks); all 16 q-blocks of one
    // K/V stream share an XCD (flat%8 invariant across q).
    const int flat = blockIdx.x;
    const int c    = flat & 31;
    const int qi   = flat >> 5;
    const int b    = c >> 2;      // KSPLIT = 4
    const int ks   = c & 3;
    const int qb   = qi * BQ;

    const float qscale = kLog2e / sdiv[0];   // exp2 domain

    const float* Qb = Qg + ((size_t)b * kSQ + qb) * kD;
    const _Float16* Khb = Kh + ((size_t)b * kSK + (size_t)ks * SKH) * kD;
    const _Float16* Vtb = Vt + (((size_t)b * 64 + (size_t)ks * (SKH / BK)) * kD) * BK;

    // ---- Q fragments: qf[mt][ds][j] = Q[q][ds*16 + hi*8 + j]*qscale,
    //      q = qb + w*64 + mt*32 + l31 (lane-col of all MFMAs) ----
    f16x8 qf[MT][4];
#pragma unroll
    for (int mt = 0; mt < MT; ++mt) {
        const float* qrow = Qb + (size_t)(w * 64 + mt * 32 + l31) * kD;
#pragma unroll
        for (int ds = 0; ds < 4; ++ds) {
            const float4 a  = *(const float4*)(qrow + ds * 16 + hi * 8);
            const float4 cc = *(const float4*)(qrow + ds * 16 + hi * 8 + 4);
            float4 as = make_float4(a.x * qscale, a.y * qscale, a.z * qscale, a.w * qscale);
            float4 cs = make_float4(cc.x * qscale, cc.y * qscale, cc.z * qscale, cc.w * qscale);
            qf[mt][ds] = pack8(as, cs);
        }
    }

    // ones A-fragment for the fused-l MFMA
    f16x8 ones;
#pragma unroll
    for (int j = 0; j < 8; ++j) ones[j] = (_Float16)1.0f;

    // Swizzled LDS fragment offsets (halves); identical pattern for K and V:
    // row = l31 (+32 for second block), 16B slot = (2*i + hi) ^ (row & 7).
    int offA[4];
#pragma unroll
    for (int i = 0; i < 4; ++i)
        offA[i] = l31 * 64 + (((2 * i + hi) ^ (l31 & 7)) * 8);

    // ---- async staging: 4 global_load_lds per wave ----
    auto stage = [&](int kt, int buf) {
        const char* gk = (const char*)(Khb + (size_t)kt * BK * kD) + w * 2048 + lane * 16;
        const char* gv = (const char*)(Vtb + (size_t)kt * kD * BK) + w * 2048 + lane * 16;
        char* lk = (char*)&sK[buf][0] + w * 2048;
        char* lv = (char*)&sV[buf][0] + w * 2048;
        gload_lds16(gk,        lk);
        gload_lds16(gk + 1024, lk + 1024);
        gload_lds16(gv,        lv);
        gload_lds16(gv + 1024, lv + 1024);
    };

    f32x16 oL[MT], oH[MT];         // O^T accumulators: d rows 0-31 / 32-63
    f32x16 ol[MT];                 // fused-l accumulator (only [0] consumed)
    float m_i[MT];
#pragma unroll
    for (int mt = 0; mt < MT; ++mt) {
        m_i[mt] = -1e30f;
#pragma unroll
        for (int r = 0; r < 16; ++r) { oL[mt][r] = 0.0f; oH[mt][r] = 0.0f; ol[mt][r] = 0.0f; }
    }

    stage(0, 0);
    __syncthreads();

    const int nIter = SKH / BK;   // 16
    for (int kt = 0; kt < nIter; ++kt) {
        const int buf = kt & 1;
        if (kt + 1 < nIter) stage(kt + 1, buf ^ 1);   // DMA in flight during compute

        // ---- kf reads: ONCE per kt, shared by both M-tiles ----
        f16x8 kf0[4], kf1[4];
#pragma unroll
        for (int ds = 0; ds < 4; ++ds) {
            kf0[ds] = *(const f16x8*)&sK[buf][offA[ds]];
            kf1[ds] = *(const f16x8*)&sK[buf][offA[ds] + 2048];
        }

        // ---- QK phase: all 16 MFMAs clustered (both M-tiles) ----
        f32x16 s0[MT], s1[MT];
#pragma unroll
        for (int mt = 0; mt < MT; ++mt)
#pragma unroll
            for (int r = 0; r < 16; ++r) { s0[mt][r] = 0.0f; s1[mt][r] = 0.0f; }

        __builtin_amdgcn_s_setprio(1);
#pragma unroll
        for (int ds = 0; ds < 4; ++ds)
#pragma unroll
            for (int mt = 0; mt < MT; ++mt) {
                s0[mt] = __builtin_amdgcn_mfma_f32_32x32x16_f16(kf0[ds], qf[mt][ds], s0[mt], 0, 0, 0);
                s1[mt] = __builtin_amdgcn_mfma_f32_32x32x16_f16(kf1[ds], qf[mt][ds], s1[mt], 0, 0, 0);
            }
        __builtin_amdgcn_s_setprio(0);

        // ---- vf reads (DS overlaps softmax VALU) ----
        f16x8 vf[4][2];
#pragma unroll
        for (int s = 0; s < 4; ++s) {
            vf[s][0] = *(const f16x8*)&sV[buf][offA[s]];
            vf[s][1] = *(const f16x8*)&sV[buf][offA[s] + 2048];
        }

#pragma unroll
        for (int mt = 0; mt < MT; ++mt) {
            // ---- in-register softmax: in-lane max tree + VALU cross-half ----
            float t[16];
#pragma unroll
            for (int r = 0; r < 16; ++r) t[r] = fmaxf(s0[mt][r], s1[mt][r]);
#pragma unroll
            for (int r = 0; r < 8; ++r)  t[r] = fmaxf(t[r], t[r + 8]);
#pragma unroll
            for (int r = 0; r < 4; ++r)  t[r] = fmaxf(t[r], t[r + 4]);
            float rm = fmaxf(fmaxf(t[0], t[1]), fmaxf(t[2], t[3]));
            rm = xhalf_max(rm);     // combine hi-halves of row q (permlane, VALU)

            // T13 defer-max: only rescale when some row's max grew > THR
            if (!__all(rm <= m_i[mt] + kDeferThr)) {
                const float mnew  = fmaxf(m_i[mt], rm);
                const float alpha = __builtin_amdgcn_exp2f(m_i[mt] - mnew);
                ol[mt][0] *= alpha;
#pragma unroll
                for (int r = 0; r < 16; ++r) { oL[mt][r] *= alpha; oH[mt][r] *= alpha; }
                m_i[mt] = mnew;
            }

#pragma unroll
            for (int r = 0; r < 16; ++r) {
                s0[mt][r] = __builtin_amdgcn_exp2f(s0[mt][r] - m_i[mt]);
                s1[mt][r] = __builtin_amdgcn_exp2f(s1[mt][r] - m_i[mt]);
            }

            // ---- P -> fp16 fragments (register-only, no LDS) ----
            f16x8 pa[4];
            PA_SLICE(pa[0], s0[mt], 0);   // keys  0-15
            PA_SLICE(pa[1], s0[mt], 8);   // keys 16-31
            PA_SLICE(pa[2], s1[mt], 0);   // keys 32-47
            PA_SLICE(pa[3], s1[mt], 8);   // keys 48-63

            // ---- PV + fused l: O^T += V^T P^T ; l += 1^T P^T ----
            __builtin_amdgcn_s_setprio(1);
#pragma unroll
            for (int s = 0; s < 4; ++s) {
                oL[mt] = __builtin_amdgcn_mfma_f32_32x32x16_f16(vf[s][0], pa[s], oL[mt], 0, 0, 0);
                oH[mt] = __builtin_amdgcn_mfma_f32_32x32x16_f16(vf[s][1], pa[s], oH[mt], 0, 0, 0);
                ol[mt] = __builtin_amdgcn_mfma_f32_32x32x16_f16(ones,     pa[s], ol[mt], 0, 0, 0);
            }
            __builtin_amdgcn_s_setprio(0);
        }

        __syncthreads();   // drains prefetch DMA (vmcnt) + LDS
    }

    // ---- epilogue: o reg r holds O[d = (r&3)+8*(r>>2)+4*hi (+32 for oH)][q].
    //      l = ol[mt][0] (MFMA summed both hi-halves). Ap stored NORMALIZED. ----
    _Float16* Ab = Ap + (size_t)ks * APART + ((size_t)b * kSQ + qb) * kD;
    float2* MLb = MLp + (size_t)ks * kB * kSQ + (size_t)b * kSQ + qb;
#pragma unroll
    for (int mt = 0; mt < MT; ++mt) {
        const int q = w * 64 + mt * 32 + l31;
        const float lf = ol[mt][0];
        const float inv = 1.0f / lf;
        _Float16* arow = &Ab[(size_t)q * kD];
#pragma unroll
        for (int g = 0; g < 4; ++g) {
            *(f16x4*)&arow[g * 8 + hi * 4] =
                pack4(oL[mt][4 * g] * inv, oL[mt][4 * g + 1] * inv,
                      oL[mt][4 * g + 2] * inv, oL[mt][4 * g + 3] * inv);
            *(f16x4*)&arow[32 + g * 8 + hi * 4] =
                pack4(oH[mt][4 * g] * inv, oH[mt][4 * g + 1] * inv,
                      oH[mt][4 * g + 2] * inv, oH[mt][4 * g + 3] * inv);
        }
        if (hi == 0) MLb[q] = make_float2(m_i[mt], lf);
    }

    // ---- fused split-K combine: last block of (b,qi) reduces all splits ----
    __threadfence();                       // release: Ap/ML visible device-wide
    if (tid == 0) sTicket = atomicAdd(&cnt[b * NQI + qi], 1);
    __syncthreads();
    if (sTicket == KSPLIT - 1) {
        __threadfence();                   // acquire: see other splits' stores
        const size_t rowb = (size_t)b * kSQ + qb;
        const int cc = (tid & 15) * 4;
#pragma unroll 1
        for (int p = 0; p < 16; ++p) {
            const int rr = (tid >> 4) + p * 16;      // 0..255
            float2 ml[KSPLIT];
            float m = -1e30f;
#pragma unroll
            for (int s = 0; s < KSPLIT; ++s) {
                ml[s] = MLp[(size_t)s * kB * kSQ + rowb + rr];
                m = fmaxf(m, ml[s].x);
            }
            float acc[4] = {0.f, 0.f, 0.f, 0.f};
            float lsum = 0.f;
#pragma unroll
            for (int s = 0; s < KSPLIT; ++s) {
                const float wgt = __builtin_amdgcn_exp2f(ml[s].x - m) * ml[s].y;
                lsum += wgt;
                const f16x4 a = *(const f16x4*)&Ap[(size_t)s * APART + (rowb + rr) * kD + cc];
#pragma unroll
                for (int j = 0; j < 4; ++j) acc[j] += wgt * (float)a[j];
            }
            const float inv = 1.0f / lsum;
            float4 res = make_float4(acc[0] * inv, acc[1] * inv, acc[2] * inv, acc[3] * inv);
            *(float4*)&Og[(rowb + rr) * kD + cc] = res;
        }
    }
}

extern "C" void kernel_launch(void* const* d_in, const int* in_sizes, int n_in,
                              void* d_out, int out_size, void* d_ws, size_t ws_size,
                              hipStream_t stream) {
    const float* Q    = (const float*)d_in[0];
    const float* K    = (const float*)d_in[1];
    const float* V    = (const float*)d_in[2];
    const float* sdiv = (const float*)d_in[4];
    float* O = (float*)d_out;

    // workspace: Kh 4MB | Vt 4MB | Ap fp16 16.8MB | MLp 1MB | cnt 512B
    _Float16* Kh  = (_Float16*)d_ws;
    _Float16* Vt  = Kh + (size_t)kB * kSK * kD;
    _Float16* Ap  = Vt + (size_t)kB * kSK * kD;
    float2*   MLp = (float2*)(Ap + (size_t)KSPLIT * APART);
    int*      cnt = (int*)(MLp + (size_t)KSPLIT * kB * kSQ);

    fattn_prepass<<<dim3(kSK / BK, kB), dim3(256), 0, stream>>>(K, V, Kh, Vt, cnt);
    fattn_partial<<<dim3((kSQ / BQ) * kB * KSPLIT), dim3(256), 0, stream>>>(Q, Kh, Vt, sdiv, Ap, MLp, cnt, O);
}

// Round 12
// 130.859 us; speedup vs baseline: 1.7411x; 1.7411x over previous
//
#include <hip/hip_runtime.h>

// Flash attention forward, fp32 in/out, fp16 MFMA compute.
// B=8, SQ=SK=4096, D=64. scores = (Q/x5) K^T ; softmax ; O = P V.
// R30 = R16 main loop + INTRA-BLOCK split-K combine (2 kernels, no fences).
// R28 evidence: (a) device-scope __threadfence forced L2 writeback -> Ap
// pushed through HBM (+16MB W, +9MB F) and staging latency poisoned the main
// loop (61->185us). (b) BUT removing the combine launch cut the fixed cost
// 72->43us -- launch-boundary overhead ~29us is the dominant non-partial
// cost. R30 gets the launch reduction WITHOUT cross-XCD coherence:
//  - 512-thr blocks (8 waves = 2/SIMD, occupancy unchanged): wave w handles
//    (ks = w&3, mhalf = w>>2); each wave runs the EXACT R16 loop (MT=2,
//    64-key kt, same tile layout/bytes). All 4 splits of (b,qi) in one block.
//  - epilogue: normalized partials (O/l fp16, m, l) -> LDS (stride 72 pads
//    16-way->2-way), __syncthreads, in-LDS combine, write O directly.
//  - deletes combine kernel + Ap/MLp traffic (17.8MB); ws -> 8.4MB.
//  - LDS 128KB static (precedent: guide's 256sq 8-phase example; AITER 160KB).
//  - grid 256 = 1 block/CU, XCD-affine by batch (b = flat&7: each batch's
//    4.2MB Kh/Vt pinned to one XCD L2).
// Kept per-wave: 32x32x16 swapped QK^T, in-register mt-interleaved softmax,
// permlane P redistribution, fused-l ones-MFMA, kf/vf once per kt, setprio
// clusters, defer-max THR=11.5, dbuf global_load_lds, launch_bounds(512,2).

typedef _Float16 f16x8 __attribute__((ext_vector_type(8)));
typedef _Float16 f16x4 __attribute__((ext_vector_type(4)));
typedef __fp16   h16x2 __attribute__((ext_vector_type(2)));
typedef float    f32x4 __attribute__((ext_vector_type(4)));
typedef float    f32x16 __attribute__((ext_vector_type(16)));

constexpr int kB  = 8;
constexpr int kSQ = 4096;
constexpr int kSK = 4096;
constexpr int kD  = 64;
constexpr int KSPLIT = 4;
constexpr int SKH = kSK / KSPLIT;     // 1024 keys per split
constexpr int BQ  = 128;              // per block: 2 mhalf x 2 M-tiles x 32 q
constexpr int MT  = 2;
constexpr int BK  = 64;
constexpr int PSTR = 72;              // LDS partial row stride (f16) - depads banks
constexpr float kLog2e = 1.44269504088896340736f;
constexpr float kDeferThr = 11.5f;    // exp2-domain (~8 nats); P <= 2^11.5

static __device__ __forceinline__ f16x4 pack4(float a, float b, float c, float d) {
    h16x2 p0 = __builtin_amdgcn_cvt_pkrtz(a, b);
    h16x2 p1 = __builtin_amdgcn_cvt_pkrtz(c, d);
    f16x4 r;
    r[0] = (_Float16)p0[0]; r[1] = (_Float16)p0[1];
    r[2] = (_Float16)p1[0]; r[3] = (_Float16)p1[1];
    return r;
}
static __device__ __forceinline__ f16x8 pack8(const float4& a, const float4& c) {
    f16x4 lo = pack4(a.x, a.y, a.z, a.w);
    f16x4 hi = pack4(c.x, c.y, c.z, c.w);
    f16x8 f;
    f[0] = lo[0]; f[1] = lo[1]; f[2] = lo[2]; f[3] = lo[3];
    f[4] = hi[0]; f[5] = hi[1]; f[6] = hi[2]; f[7] = hi[3];
    return f;
}
static __device__ __forceinline__ unsigned pkrtz_u(float a, float b) {
    union { h16x2 h; unsigned u; } cv;
    cv.h = __builtin_amdgcn_cvt_pkrtz(a, b);
    return cv.u;
}
static __device__ __forceinline__ float xhalf_max(float x) {
    // max(x[lane], x[lane^32]) in every lane, VALU-only.
    union { float f; unsigned u; } uv; uv.f = x;
    auto pr = __builtin_amdgcn_permlane32_swap(uv.u, uv.u, false, false);
    union { unsigned u; float f; } r0, r1;
    r0.u = pr[0]; r1.u = pr[1];
    return fmaxf(r0.f, r1.f);
}

typedef const __attribute__((address_space(1))) unsigned int* gu32p;
typedef __attribute__((address_space(3))) unsigned int* lu32p;
static __device__ __forceinline__ void gload_lds16(const void* g, void* l) {
    __builtin_amdgcn_global_load_lds((gu32p)g, (lu32p)l, 16, 0, 0);
}

// P slice (8 regs of one 32-key C-block) -> f16x8 PV fragment.
#define PA_SLICE(dst, sv, rb) do {                                          \
    unsigned c0 = pkrtz_u((sv)[(rb)+0], (sv)[(rb)+1]);                      \
    unsigned c1 = pkrtz_u((sv)[(rb)+2], (sv)[(rb)+3]);                      \
    unsigned c2 = pkrtz_u((sv)[(rb)+4], (sv)[(rb)+5]);                      \
    unsigned c3 = pkrtz_u((sv)[(rb)+6], (sv)[(rb)+7]);                      \
    auto r02 = __builtin_amdgcn_permlane32_swap(c0, c2, false, false);      \
    auto r13 = __builtin_amdgcn_permlane32_swap(c1, c3, false, false);      \
    union { unsigned u[4]; f16x8 v; } _r;                                   \
    _r.u[0] = r02[0]; _r.u[1] = r13[0]; _r.u[2] = r02[1]; _r.u[3] = r13[1]; \
    dst = _r.v;                                                             \
} while (0)

// ---------------- pre-pass: K -> Kh (swizzled fp16), V -> Vt (transposed,
// tiled, swizzled fp16). Kh[b][k][blk fb^(k&7)][8]; Vt[b][kt][f][blk kb^(f&7)][8].
__global__ __launch_bounds__(256, 2)
void fattn_prepass(const float* __restrict__ Kg,
                   const float* __restrict__ Vg,
                   _Float16* __restrict__ Kh,
                   _Float16* __restrict__ Vt)
{
    __shared__ _Float16 tr[kD][BK];

    const int tid = threadIdx.x;
    const int kt  = blockIdx.x;
    const int b   = blockIdx.y;

    const int k = tid >> 2;
    const int p = tid & 3;
    const int gk = kt * BK + k;

    {
        const float* src = Kg + ((size_t)b * kSK + gk) * kD + p * 16;
        const float4 a0 = *(const float4*)(src + 0);
        const float4 a1 = *(const float4*)(src + 4);
        const float4 a2 = *(const float4*)(src + 8);
        const float4 a3 = *(const float4*)(src + 12);
        _Float16* dst = Kh + ((size_t)b * kSK + gk) * kD;
        const int fb0 = 2 * p, fb1 = 2 * p + 1;
        *(f16x8*)&dst[(fb0 ^ (gk & 7)) * 8] = pack8(a0, a1);
        *(f16x8*)&dst[(fb1 ^ (gk & 7)) * 8] = pack8(a2, a3);
    }
    {
        const float* src = Vg + ((size_t)b * kSK + gk) * kD + p * 16;
        const float4 a0 = *(const float4*)(src + 0);
        const float4 a1 = *(const float4*)(src + 4);
        const float4 a2 = *(const float4*)(src + 8);
        const float4 a3 = *(const float4*)(src + 12);
        const float v[16] = {a0.x,a0.y,a0.z,a0.w, a1.x,a1.y,a1.z,a1.w,
                             a2.x,a2.y,a2.z,a2.w, a3.x,a3.y,a3.z,a3.w};
#pragma unroll
        for (int j = 0; j < 16; ++j)
            tr[p * 16 + j][k] = (_Float16)v[j];
    }
    __syncthreads();
    {
        const int f  = tid >> 2;
        const int p2 = tid & 3;
        const f16x8 b0 = *(const f16x8*)&tr[f][p2 * 16 + 0];
        const f16x8 b1 = *(const f16x8*)&tr[f][p2 * 16 + 8];
        _Float16* dst = Vt + (((size_t)b * 64 + kt) * kD + f) * BK;
        const int kb0 = 2 * p2, kb1 = 2 * p2 + 1;
        *(f16x8*)&dst[(kb0 ^ (f & 7)) * 8] = b0;
        *(f16x8*)&dst[(kb1 ^ (f & 7)) * 8] = b1;
    }
}

// ---------------- fused partial+combine kernel (8 waves, 4 splits in-block) ----------------
__global__ __launch_bounds__(512, 2)
void fattn_fused(const float* __restrict__ Qg,
                 const _Float16* __restrict__ Kh,
                 const _Float16* __restrict__ Vt,
                 const float* __restrict__ sdiv,
                 float* __restrict__ Og)
{
    // 128 KB: main loop sK[4][2][4096] | sV[4][2][4096];
    // epilogue overlay: sPart[2][4][64][PSTR] f16 + sMl[2][4][64] float2
    __shared__ __align__(16) char smem[131072];
    _Float16* sKb = (_Float16*)smem;                   // K streams, 64 KB
    _Float16* sVb = (_Float16*)(smem + 65536);         // V streams, 64 KB
    _Float16* sPart = (_Float16*)smem;                 // [2][4][64][PSTR]
    float2*   sMl   = (float2*)(smem + (size_t)2 * 4 * 64 * PSTR * 2);  // +4KB

    const int tid  = threadIdx.x;
    const int w    = tid >> 6;      // 0..7
    const int lane = tid & 63;
    const int l31  = lane & 31;
    const int hi   = lane >> 5;
    const int ks   = w & 3;         // split
    const int mh   = w >> 2;        // q-half (0/1)

    // XCD-affine decode: b = flat&7 -> all 32 blocks of a batch on one XCD.
    const int flat = blockIdx.x;
    const int b    = flat & 7;
    const int qi   = flat >> 3;
    const int qb   = qi * BQ;

    const float qscale = kLog2e / sdiv[0];   // exp2 domain

    const float* Qb = Qg + ((size_t)b * kSQ + qb) * kD;
    const _Float16* Khb = Kh + ((size_t)b * kSK + (size_t)ks * SKH) * kD;
    const _Float16* Vtb = Vt + (((size_t)b * 64 + (size_t)ks * (SKH / BK)) * kD) * BK;

    _Float16* sK = sKb + (ks * 2) * 4096;    // this stream's dbuf base
    _Float16* sV = sVb + (ks * 2) * 4096;

    // ---- Q fragments: q = qb + mh*64 + mt*32 + l31 ----
    f16x8 qf[MT][4];
#pragma unroll
    for (int mt = 0; mt < MT; ++mt) {
        const float* qrow = Qb + (size_t)(mh * 64 + mt * 32 + l31) * kD;
#pragma unroll
        for (int ds = 0; ds < 4; ++ds) {
            const float4 a  = *(const float4*)(qrow + ds * 16 + hi * 8);
            const float4 cc = *(const float4*)(qrow + ds * 16 + hi * 8 + 4);
            float4 as = make_float4(a.x * qscale, a.y * qscale, a.z * qscale, a.w * qscale);
            float4 cs = make_float4(cc.x * qscale, cc.y * qscale, cc.z * qscale, cc.w * qscale);
            qf[mt][ds] = pack8(as, cs);
        }
    }

    // ones A-fragment for the fused-l MFMA
    f16x8 ones;
#pragma unroll
    for (int j = 0; j < 8; ++j) ones[j] = (_Float16)1.0f;

    // Swizzled LDS fragment offsets (same tile layout as R16).
    int offA[4];
#pragma unroll
    for (int i = 0; i < 4; ++i)
        offA[i] = l31 * 64 + (((2 * i + hi) ^ (l31 & 7)) * 8);

    // ---- staging: stream ks staged by its 2 waves (mh 0/1), 8 loads/wave ----
    auto stage = [&](int kt, int buf) {
        const char* gk = (const char*)(Khb + (size_t)kt * BK * kD) + mh * 4096 + lane * 16;
        const char* gv = (const char*)(Vtb + (size_t)kt * kD * BK) + mh * 4096 + lane * 16;
        char* lk = (char*)&sK[buf * 4096] + mh * 4096;
        char* lv = (char*)&sV[buf * 4096] + mh * 4096;
        gload_lds16(gk,        lk);
        gload_lds16(gk + 1024, lk + 1024);
        gload_lds16(gk + 2048, lk + 2048);
        gload_lds16(gk + 3072, lk + 3072);
        gload_lds16(gv,        lv);
        gload_lds16(gv + 1024, lv + 1024);
        gload_lds16(gv + 2048, lv + 2048);
        gload_lds16(gv + 3072, lv + 3072);
    };

    f32x16 oL[MT], oH[MT];
    f32x16 ol[MT];
    float m_i[MT];
#pragma unroll
    for (int mt = 0; mt < MT; ++mt) {
        m_i[mt] = -1e30f;
#pragma unroll
        for (int r = 0; r < 16; ++r) { oL[mt][r] = 0.0f; oH[mt][r] = 0.0f; ol[mt][r] = 0.0f; }
    }

    stage(0, 0);
    __syncthreads();

    const int nIter = SKH / BK;   // 16
    for (int kt = 0; kt < nIter; ++kt) {
        const int buf = kt & 1;
        if (kt + 1 < nIter) stage(kt + 1, buf ^ 1);

        // ---- kf reads: ONCE per kt, shared by both M-tiles ----
        f16x8 kf0[4], kf1[4];
#pragma unroll
        for (int ds = 0; ds < 4; ++ds) {
            kf0[ds] = *(const f16x8*)&sK[buf * 4096 + offA[ds]];
            kf1[ds] = *(const f16x8*)&sK[buf * 4096 + offA[ds] + 2048];
        }

        // ---- QK phase ----
        f32x16 s0[MT], s1[MT];
#pragma unroll
        for (int mt = 0; mt < MT; ++mt)
#pragma unroll
            for (int r = 0; r < 16; ++r) { s0[mt][r] = 0.0f; s1[mt][r] = 0.0f; }

        __builtin_amdgcn_s_setprio(1);
#pragma unroll
        for (int ds = 0; ds < 4; ++ds)
#pragma unroll
            for (int mt = 0; mt < MT; ++mt) {
                s0[mt] = __builtin_amdgcn_mfma_f32_32x32x16_f16(kf0[ds], qf[mt][ds], s0[mt], 0, 0, 0);
                s1[mt] = __builtin_amdgcn_mfma_f32_32x32x16_f16(kf1[ds], qf[mt][ds], s1[mt], 0, 0, 0);
            }
        __builtin_amdgcn_s_setprio(0);

        // ---- vf reads ----
        f16x8 vf[4][2];
#pragma unroll
        for (int s = 0; s < 4; ++s) {
            vf[s][0] = *(const f16x8*)&sV[buf * 4096 + offA[s]];
            vf[s][1] = *(const f16x8*)&sV[buf * 4096 + offA[s] + 2048];
        }

#pragma unroll
        for (int mt = 0; mt < MT; ++mt) {
            // ---- in-register softmax ----
            float t[16];
#pragma unroll
            for (int r = 0; r < 16; ++r) t[r] = fmaxf(s0[mt][r], s1[mt][r]);
#pragma unroll
            for (int r = 0; r < 8; ++r)  t[r] = fmaxf(t[r], t[r + 8]);
#pragma unroll
            for (int r = 0; r < 4; ++r)  t[r] = fmaxf(t[r], t[r + 4]);
            float rm = fmaxf(fmaxf(t[0], t[1]), fmaxf(t[2], t[3]));
            rm = xhalf_max(rm);

            if (!__all(rm <= m_i[mt] + kDeferThr)) {
                const float mnew  = fmaxf(m_i[mt], rm);
                const float alpha = __builtin_amdgcn_exp2f(m_i[mt] - mnew);
                ol[mt][0] *= alpha;
#pragma unroll
                for (int r = 0; r < 16; ++r) { oL[mt][r] *= alpha; oH[mt][r] *= alpha; }
                m_i[mt] = mnew;
            }

#pragma unroll
            for (int r = 0; r < 16; ++r) {
                s0[mt][r] = __builtin_amdgcn_exp2f(s0[mt][r] - m_i[mt]);
                s1[mt][r] = __builtin_amdgcn_exp2f(s1[mt][r] - m_i[mt]);
            }

            // ---- P -> fp16 fragments ----
            f16x8 pa[4];
            PA_SLICE(pa[0], s0[mt], 0);
            PA_SLICE(pa[1], s0[mt], 8);
            PA_SLICE(pa[2], s1[mt], 0);
            PA_SLICE(pa[3], s1[mt], 8);

            // ---- PV + fused l ----
            __builtin_amdgcn_s_setprio(1);
#pragma unroll
            for (int s = 0; s < 4; ++s) {
                oL[mt] = __builtin_amdgcn_mfma_f32_32x32x16_f16(vf[s][0], pa[s], oL[mt], 0, 0, 0);
                oH[mt] = __builtin_amdgcn_mfma_f32_32x32x16_f16(vf[s][1], pa[s], oH[mt], 0, 0, 0);
                ol[mt] = __builtin_amdgcn_mfma_f32_32x32x16_f16(ones,     pa[s], ol[mt], 0, 0, 0);
            }
            __builtin_amdgcn_s_setprio(0);
        }

        __syncthreads();
    }

    // ---- epilogue 1: normalized partials -> LDS (overlay; all sK reads done) ----
    // sPart[mh][ks][qlocal][d] (stride PSTR), sMl[mh][ks][qlocal]
#pragma unroll
    for (int mt = 0; mt < MT; ++mt) {
        const int ql = mt * 32 + l31;            // 0..63
        const float lf = ol[mt][0];
        const float inv = 1.0f / lf;
        _Float16* prow = sPart + ((size_t)(mh * 4 + ks) * 64 + ql) * PSTR;
#pragma unroll
        for (int g = 0; g < 4; ++g) {
            *(f16x4*)&prow[g * 8 + hi * 4] =
                pack4(oL[mt][4 * g] * inv, oL[mt][4 * g + 1] * inv,
                      oL[mt][4 * g + 2] * inv, oL[mt][4 * g + 3] * inv);
            *(f16x4*)&prow[32 + g * 8 + hi * 4] =
                pack4(oH[mt][4 * g] * inv, oH[mt][4 * g + 1] * inv,
                      oH[mt][4 * g + 2] * inv, oH[mt][4 * g + 3] * inv);
        }
        if (hi == 0) sMl[(mh * 4 + ks) * 64 + ql] = make_float2(m_i[mt], lf);
    }
    __syncthreads();

    // ---- epilogue 2: in-LDS combine, write O ----
    {
        const int qrow = tid >> 2;               // 0..127
        const int cc   = (tid & 3) * 16;         // 16 cols per thread
        const int emh  = qrow >> 6;
        const int eql  = qrow & 63;

        float2 ml[KSPLIT];
        float m = -1e30f;
#pragma unroll
        for (int s = 0; s < KSPLIT; ++s) {
            ml[s] = sMl[(emh * 4 + s) * 64 + eql];
            m = fmaxf(m, ml[s].x);
        }
        float wgt[KSPLIT];
        float lsum = 0.f;
#pragma unroll
        for (int s = 0; s < KSPLIT; ++s) {
            wgt[s] = __builtin_amdgcn_exp2f(ml[s].x - m) * ml[s].y;
            lsum += wgt[s];
        }
        const float inv = 1.0f / lsum;

        float* orow = Og + (((size_t)b * kSQ + qb + qrow)) * kD + cc;
#pragma unroll
        for (int j = 0; j < 4; ++j) {
            float a0 = 0.f, a1 = 0.f, a2 = 0.f, a3 = 0.f;
#pragma unroll
            for (int s = 0; s < KSPLIT; ++s) {
                const f16x4 a = *(const f16x4*)&sPart[((size_t)(emh * 4 + s) * 64 + eql) * PSTR + cc + j * 4];
                a0 += wgt[s] * (float)a[0];
                a1 += wgt[s] * (float)a[1];
                a2 += wgt[s] * (float)a[2];
                a3 += wgt[s] * (float)a[3];
            }
            *(float4*)&orow[j * 4] = make_float4(a0 * inv, a1 * inv, a2 * inv, a3 * inv);
        }
    }
}

extern "C" void kernel_launch(void* const* d_in, const int* in_sizes, int n_in,
                              void* d_out, int out_size, void* d_ws, size_t ws_size,
                              hipStream_t stream) {
    const float* Q    = (const float*)d_in[0];
    const float* K    = (const float*)d_in[1];
    const float* V    = (const float*)d_in[2];
    const float* sdiv = (const float*)d_in[4];
    float* O = (float*)d_out;

    // workspace: Kh 4MB | Vt 4MB
    _Float16* Kh  = (_Float16*)d_ws;
    _Float16* Vt  = Kh + (size_t)kB * kSK * kD;

    fattn_prepass<<<dim3(kSK / BK, kB), dim3(256), 0, stream>>>(K, V, Kh, Vt);
    fattn_fused<<<dim3(kB * (kSQ / BQ)), dim3(512), 0, stream>>>(Q, Kh, Vt, sdiv, O);
}